// Round 5
// baseline (192.854 us; speedup 1.0000x reference)
//
#include <hip/hip_runtime.h>
#include <hip/hip_bf16.h>
#include <stdint.h>

// PSM cosine cost volume, MI355X (gfx950).
// out[b,d,h,w] = (1/C) * sum_c L[b,c,h,w] * R[b,c,h,w-d],  0 where w<d.
// Banded Gram matrix via bf16 MFMA 16x16x32. One block per (b,h,half-row).
//
// R5: T14 async-STAGE pipeline. Each thread prefetches chunk k+1's 14 float4s
// into registers right after chunk k's LDS writes; the pack+ds_write of chunk
// k+1 then waits on loads that have had compute + 2 barriers to arrive.
//
// LDS layout, per row lw (128B = 64 bf16 = KC channels), 16B slot s holds
// c in [8s',8s'+8) where s = s' ^ (lw&7) ^ ((lw>>4)&7):
//   (lw&7): read-side spread; ((lw>>4)&7): write-side spread, wave-uniform at
//   read (tile index) so fragment reads stay single ds_read_b128.
// Dword within slot = c-pair index (rp&3); bf16 pair = (even c, odd c).

#define B_ 4
#define C_ 512
#define H_ 96
#define W_ 312
#define D_ 48
#define HW_ (H_ * W_)      // 29952
#define CHW_ (C_ * HW_)

#define KC 64              // staged c per chunk
#define NCHUNK (C_ / KC)   // 8
#define HALFW 156          // output w span per block
#define LCOLS 160          // staged L columns (10 N-tiles of 16)
#define RCOLS 208          // staged R columns ([wb-48, wb+160))
#define PITCH 128          // LDS row pitch bytes (64 bf16 = KC)
#define LBYTES (LCOLS * PITCH)          // 20480
#define RBYTES (RCOLS * PITCH)          // 26624
#define SMEM_BYTES (LBYTES + RBYTES)    // 47104

#define LITEMS 3           // ceil(32*40 / 512)
#define RITEMS 4           // ceil(32*52 / 512)

typedef __bf16 bf16x8 __attribute__((ext_vector_type(8)));
typedef float  f32x4  __attribute__((ext_vector_type(4)));

__device__ __forceinline__ uint32_t pack2_bf16(float a, float b) {
    // RNE f32 -> bf16 pair (a = low half = even c)
    uint32_t ua = __builtin_bit_cast(uint32_t, a);
    uint32_t ub = __builtin_bit_cast(uint32_t, b);
    ua += 0x7FFFu + ((ua >> 16) & 1u);
    ub += 0x7FFFu + ((ub >> 16) & 1u);
    return (ua >> 16) | (ub & 0xFFFF0000u);
}

// Byte offset of the 16B slot holding c-range [8*chi, 8*chi+8) of row lw.
__device__ __forceinline__ int lds_slotoff(int lw, int chi) {
    return lw * PITCH + ((chi ^ (lw & 7) ^ ((lw >> 4) & 7)) << 4);
}

__global__ __launch_bounds__(512, 4)
void psm_cost_volume(const float* __restrict__ lf,
                     const float* __restrict__ rf,
                     float* __restrict__ out) {
    const int half = blockIdx.x;        // 0,1
    const int h    = blockIdx.y;
    const int b    = blockIdx.z;
    const int wb   = half * HALFW;
    const int tid  = threadIdx.x;
    const int lane = tid & 63;
    const int wave = tid >> 6;          // 8 waves
    const int l15  = lane & 15;
    const int l4   = lane >> 4;
    const int jj   = wave & 3;          // A-tile offset
    const int nb   = wave >> 2;         // n = 2*pi + nb

    extern __shared__ char smem[];

    const float* lbase = lf + (size_t)b * CHW_ + (size_t)h * W_;
    const float* rbase = rf + (size_t)b * CHW_ + (size_t)h * W_;

    f32x4 acc[5];
    #pragma unroll
    for (int i = 0; i < 5; ++i) acc[i] = f32x4{0.f, 0.f, 0.f, 0.f};

    // prefetch registers (one chunk deep)
    f32x4 pl0[LITEMS], pl1[LITEMS], pr0[RITEMS], pr1[RITEMS];

    // ---- issue loads for chunk c0 into prefetch regs ----
    auto LOADS = [&](int c0) {
        #pragma unroll
        for (int it = 0; it < LITEMS; ++it) {
            int idx = tid + it * 512;
            if (idx < 32 * 40) {
                int rp = idx / 40;
                int q  = idx - rp * 40;
                int w4 = wb + 4 * q;
                pl0[it] = f32x4{0.f, 0.f, 0.f, 0.f};
                pl1[it] = f32x4{0.f, 0.f, 0.f, 0.f};
                if (w4 + 3 < W_) {
                    const float* g = lbase + (size_t)(c0 + 2 * rp) * HW_ + w4;
                    pl0[it] = *(const f32x4*)g;
                    pl1[it] = *(const f32x4*)(g + HW_);
                }
            }
        }
        #pragma unroll
        for (int it = 0; it < RITEMS; ++it) {
            int idx = tid + it * 512;
            if (idx < 32 * 52) {
                int rp = idx / 52;
                int q  = idx - rp * 52;
                int w4 = wb - 48 + 4 * q;
                pr0[it] = f32x4{0.f, 0.f, 0.f, 0.f};
                pr1[it] = f32x4{0.f, 0.f, 0.f, 0.f};
                if (w4 >= 0 && w4 + 3 < W_) {
                    const float* g = rbase + (size_t)(c0 + 2 * rp) * HW_ + w4;
                    pr0[it] = *(const f32x4*)g;
                    pr1[it] = *(const f32x4*)(g + HW_);
                }
            }
        }
    };

    // ---- pack prefetch regs -> LDS (waits on their loads) ----
    auto WRITES = [&]() {
        #pragma unroll
        for (int it = 0; it < LITEMS; ++it) {
            int idx = tid + it * 512;
            if (idx < 32 * 40) {
                int rp  = idx / 40;
                int q   = idx - rp * 40;
                int chi = rp >> 2;
                int cb  = (rp & 3) << 2;
                #pragma unroll
                for (int j = 0; j < 4; ++j) {
                    int lw = 4 * q + j;
                    *(uint32_t*)(smem + lds_slotoff(lw, chi) + cb) =
                        pack2_bf16(pl0[it][j], pl1[it][j]);
                }
            }
        }
        #pragma unroll
        for (int it = 0; it < RITEMS; ++it) {
            int idx = tid + it * 512;
            if (idx < 32 * 52) {
                int rp  = idx / 52;
                int q   = idx - rp * 52;
                int chi = rp >> 2;
                int cb  = (rp & 3) << 2;
                #pragma unroll
                for (int j = 0; j < 4; ++j) {
                    int lw = 4 * q + j;
                    *(uint32_t*)(smem + LBYTES + lds_slotoff(lw, chi) + cb) =
                        pack2_bf16(pr0[it][j], pr1[it][j]);
                }
            }
        }
    };

    LOADS(0);
    for (int ch = 0; ch < NCHUNK; ++ch) {
        if (ch) __syncthreads();        // all waves done reading LDS of ch-1
        WRITES();                       // stage chunk ch (vmcnt-waits its loads)
        if (ch + 1 < NCHUNK) LOADS((ch + 1) * KC);   // in flight across compute
        __syncthreads();

        // ---- compute: 5 (n,jj) pairs per wave, all reads ds_read_b128 ----
        #pragma unroll
        for (int ks = 0; ks < 2; ++ks) {
            const int chi = ks * 4 + l4;
            #pragma unroll
            for (int pi = 0; pi < 5; ++pi) {
                const int n   = 2 * pi + nb;
                const int lwB = 16 * n + l15;
                const int lwA = 16 * (n + jj) + l15;
                bf16x8 bfrag = *(const bf16x8*)(smem + lds_slotoff(lwB, chi));
                bf16x8 afrag = *(const bf16x8*)(smem + LBYTES + lds_slotoff(lwA, chi));
                acc[pi] = __builtin_amdgcn_mfma_f32_16x16x32_bf16(afrag, bfrag, acc[pi], 0, 0, 0);
            }
        }
    }
    __syncthreads();

    // ---- scatter accumulators -> LDS [D_][HALFW] f32 ----
    // D[m][n]: col tn = l15, row tm = 4*l4 + r.
    // w = wb + 16n + tn ; w' = wb - 48 + 16(n+jj) + tm ; d = 48 - 16*jj + tn - tm
    float* outs = (float*)smem;
    #pragma unroll
    for (int pi = 0; pi < 5; ++pi) {
        const int n  = 2 * pi + nb;
        const int lw = 16 * n + l15;
        #pragma unroll
        for (int r = 0; r < 4; ++r) {
            int tm = 4 * l4 + r;
            int d  = 48 - 16 * jj + l15 - tm;
            if (d >= 0 && d < D_ && lw < HALFW) {
                outs[d * HALFW + lw] = acc[pi][r] * (1.f / 512.f);
            }
        }
    }
    __syncthreads();

    // ---- coalesced global store ----
    float* obase = out + (size_t)b * (D_ * HW_) + (size_t)h * W_ + wb;
    for (int idx = tid; idx < D_ * HALFW; idx += 512) {
        int d  = idx / HALFW;
        int lw = idx - d * HALFW;
        obase[(size_t)d * HW_ + lw] = outs[idx];
    }
}

extern "C" void kernel_launch(void* const* d_in, const int* in_sizes, int n_in,
                              void* d_out, int out_size, void* d_ws, size_t ws_size,
                              hipStream_t stream) {
    const float* lf = (const float*)d_in[0];
    const float* rf = (const float*)d_in[1];
    float* out = (float*)d_out;
    dim3 grid(2, H_, B_);   // 768 blocks
    psm_cost_volume<<<grid, 512, SMEM_BYTES, stream>>>(lf, rf, out);
}

// Round 6
// 112.145 us; speedup vs baseline: 1.7197x; 1.7197x over previous
//
#include <hip/hip_runtime.h>
#include <hip/hip_bf16.h>
#include <stdint.h>

// PSM cosine cost volume, MI355X (gfx950).
// out[b,d,h,w] = (1/C) * sum_c L[b,c,h,w] * R[b,c,h,w-d],  0 where w<d.
// Banded Gram matrix via bf16 MFMA 16x16x32. One block per (b,h,half-row).
//
// R6: true async-STAGE pipeline.
//  - register prefetch one chunk deep (loads issued after chunk k's ds_writes,
//    consumed by chunk k+1's ds_writes — in flight across compute + barriers)
//  - raw s_barrier + lgkmcnt(0)-only drains in the main loop (NO vmcnt drain:
//    __syncthreads would kill the prefetch by draining vmcnt(0) at the barrier)
//  - __launch_bounds__(512,2): R5's (512,4) hard-capped VGPR at 64 and spilled
//    the prefetch to scratch (+150MB scratch traffic).
//
// LDS layout, per row lw (128B = 64 bf16 = KC channels), 16B slot s holds
// c in [8s',8s'+8) where s = s' ^ (lw&7) ^ ((lw>>4)&7):
//   (lw&7): read-side spread; ((lw>>4)&7): write-side spread, wave-uniform at
//   read (tile index) so fragment reads stay single ds_read_b128.
// Dword within slot = c-pair index (rp&3); bf16 pair = (even c, odd c).

#define B_ 4
#define C_ 512
#define H_ 96
#define W_ 312
#define D_ 48
#define HW_ (H_ * W_)      // 29952
#define CHW_ (C_ * HW_)

#define KC 64              // staged c per chunk
#define NCHUNK (C_ / KC)   // 8
#define HALFW 156          // output w span per block
#define LCOLS 160          // staged L columns (10 N-tiles of 16)
#define RCOLS 208          // staged R columns ([wb-48, wb+160))
#define PITCH 128          // LDS row pitch bytes (64 bf16 = KC)
#define LBYTES (LCOLS * PITCH)          // 20480
#define RBYTES (RCOLS * PITCH)          // 26624
#define SMEM_BYTES (LBYTES + RBYTES)    // 47104

#define LITEMS 3           // ceil(32*40 / 512)
#define RITEMS 4           // ceil(32*52 / 512)

typedef __bf16 bf16x8 __attribute__((ext_vector_type(8)));
typedef float  f32x4  __attribute__((ext_vector_type(4)));

__device__ __forceinline__ uint32_t pack2_bf16(float a, float b) {
    // RNE f32 -> bf16 pair (a = low half = even c)
    uint32_t ua = __builtin_bit_cast(uint32_t, a);
    uint32_t ub = __builtin_bit_cast(uint32_t, b);
    ua += 0x7FFFu + ((ua >> 16) & 1u);
    ub += 0x7FFFu + ((ub >> 16) & 1u);
    return (ua >> 16) | (ub & 0xFFFF0000u);
}

// Byte offset of the 16B slot holding c-range [8*chi, 8*chi+8) of row lw.
__device__ __forceinline__ int lds_slotoff(int lw, int chi) {
    return lw * PITCH + ((chi ^ (lw & 7) ^ ((lw >> 4) & 7)) << 4);
}

// LDS-only drain + barrier (keeps global loads in flight across the barrier).
__device__ __forceinline__ void lds_barrier() {
    asm volatile("s_waitcnt lgkmcnt(0)" ::: "memory");
    __builtin_amdgcn_s_barrier();
}

__global__ __launch_bounds__(512, 2)
void psm_cost_volume(const float* __restrict__ lf,
                     const float* __restrict__ rf,
                     float* __restrict__ out) {
    const int half = blockIdx.x;        // 0,1
    const int h    = blockIdx.y;
    const int b    = blockIdx.z;
    const int wb   = half * HALFW;
    const int tid  = threadIdx.x;
    const int lane = tid & 63;
    const int wave = tid >> 6;          // 8 waves
    const int l15  = lane & 15;
    const int l4   = lane >> 4;
    const int jj   = wave & 3;          // A-tile offset
    const int nb   = wave >> 2;         // n = 2*pi + nb

    extern __shared__ char smem[];

    const float* lbase = lf + (size_t)b * CHW_ + (size_t)h * W_;
    const float* rbase = rf + (size_t)b * CHW_ + (size_t)h * W_;

    f32x4 acc[5];
    #pragma unroll
    for (int i = 0; i < 5; ++i) acc[i] = f32x4{0.f, 0.f, 0.f, 0.f};

    // prefetch registers (one chunk deep): 14 float4 = 56 VGPR
    f32x4 pl0[LITEMS], pl1[LITEMS], pr0[RITEMS], pr1[RITEMS];

    // ---- issue loads for chunk starting at channel c0 into prefetch regs ----
    auto LOADS = [&](int c0) {
        #pragma unroll
        for (int it = 0; it < LITEMS; ++it) {
            int idx = tid + it * 512;
            if (idx < 32 * 40) {               // wave-uniform guard (it=2: waves 0-3)
                int rp = idx / 40;
                int q  = idx - rp * 40;
                int w4 = wb + 4 * q;
                pl0[it] = f32x4{0.f, 0.f, 0.f, 0.f};
                pl1[it] = f32x4{0.f, 0.f, 0.f, 0.f};
                if (w4 + 3 < W_) {
                    const float* g = lbase + (size_t)(c0 + 2 * rp) * HW_ + w4;
                    pl0[it] = *(const f32x4*)g;
                    pl1[it] = *(const f32x4*)(g + HW_);
                }
            }
        }
        #pragma unroll
        for (int it = 0; it < RITEMS; ++it) {
            int idx = tid + it * 512;
            if (idx < 32 * 52) {               // wave-uniform guard (it=3: waves 0-1)
                int rp = idx / 52;
                int q  = idx - rp * 52;
                int w4 = wb - 48 + 4 * q;
                pr0[it] = f32x4{0.f, 0.f, 0.f, 0.f};
                pr1[it] = f32x4{0.f, 0.f, 0.f, 0.f};
                if (w4 >= 0 && w4 + 3 < W_) {
                    const float* g = rbase + (size_t)(c0 + 2 * rp) * HW_ + w4;
                    pr0[it] = *(const f32x4*)g;
                    pr1[it] = *(const f32x4*)(g + HW_);
                }
            }
        }
    };

    // ---- pack prefetch regs -> LDS (vmcnt-waits exactly the loads consumed) ----
    auto WRITES = [&]() {
        #pragma unroll
        for (int it = 0; it < LITEMS; ++it) {
            int idx = tid + it * 512;
            if (idx < 32 * 40) {
                int rp  = idx / 40;
                int q   = idx - rp * 40;
                int chi = rp >> 2;
                int cb  = (rp & 3) << 2;
                #pragma unroll
                for (int j = 0; j < 4; ++j) {
                    int lw = 4 * q + j;
                    *(uint32_t*)(smem + lds_slotoff(lw, chi) + cb) =
                        pack2_bf16(pl0[it][j], pl1[it][j]);
                }
            }
        }
        #pragma unroll
        for (int it = 0; it < RITEMS; ++it) {
            int idx = tid + it * 512;
            if (idx < 32 * 52) {
                int rp  = idx / 52;
                int q   = idx - rp * 52;
                int chi = rp >> 2;
                int cb  = (rp & 3) << 2;
                #pragma unroll
                for (int j = 0; j < 4; ++j) {
                    int lw = 4 * q + j;
                    *(uint32_t*)(smem + LBYTES + lds_slotoff(lw, chi) + cb) =
                        pack2_bf16(pr0[it][j], pr1[it][j]);
                }
            }
        }
    };

    LOADS(0);
    for (int ch = 0; ch < NCHUNK; ++ch) {
        if (ch) lds_barrier();          // all waves done reading chunk ch-1's LDS
        WRITES();                       // stage chunk ch from prefetch regs
        if (ch + 1 < NCHUNK) LOADS((ch + 1) * KC);  // in flight across barriers+compute
        lds_barrier();                  // ds_writes visible; vmcnt NOT drained

        // ---- compute: 5 (n,jj) pairs per wave, all reads ds_read_b128 ----
        #pragma unroll
        for (int ks = 0; ks < 2; ++ks) {
            const int chi = ks * 4 + l4;
            #pragma unroll
            for (int pi = 0; pi < 5; ++pi) {
                const int n   = 2 * pi + nb;
                const int lwB = 16 * n + l15;
                const int lwA = 16 * (n + jj) + l15;
                bf16x8 bfrag = *(const bf16x8*)(smem + lds_slotoff(lwB, chi));
                bf16x8 afrag = *(const bf16x8*)(smem + LBYTES + lds_slotoff(lwA, chi));
                acc[pi] = __builtin_amdgcn_mfma_f32_16x16x32_bf16(afrag, bfrag, acc[pi], 0, 0, 0);
            }
        }
    }
    __syncthreads();   // epilogue overwrites LDS; nothing left in flight

    // ---- scatter accumulators -> LDS [D_][HALFW] f32 ----
    // D[m][n]: col tn = l15, row tm = 4*l4 + r.
    // w = wb + 16n + tn ; w' = wb - 48 + 16(n+jj) + tm ; d = 48 - 16*jj + tn - tm
    float* outs = (float*)smem;
    #pragma unroll
    for (int pi = 0; pi < 5; ++pi) {
        const int n  = 2 * pi + nb;
        const int lw = 16 * n + l15;
        #pragma unroll
        for (int r = 0; r < 4; ++r) {
            int tm = 4 * l4 + r;
            int d  = 48 - 16 * jj + l15 - tm;
            if (d >= 0 && d < D_ && lw < HALFW) {
                outs[d * HALFW + lw] = acc[pi][r] * (1.f / 512.f);
            }
        }
    }
    __syncthreads();

    // ---- coalesced global store ----
    float* obase = out + (size_t)b * (D_ * HW_) + (size_t)h * W_ + wb;
    for (int idx = tid; idx < D_ * HALFW; idx += 512) {
        int d  = idx / HALFW;
        int lw = idx - d * HALFW;
        obase[(size_t)d * HW_ + lw] = outs[idx];
    }
}

extern "C" void kernel_launch(void* const* d_in, const int* in_sizes, int n_in,
                              void* d_out, int out_size, void* d_ws, size_t ws_size,
                              hipStream_t stream) {
    const float* lf = (const float*)d_in[0];
    const float* rf = (const float*)d_in[1];
    float* out = (float*)d_out;
    dim3 grid(2, H_, B_);   // 768 blocks
    psm_cost_volume<<<grid, 512, SMEM_BYTES, stream>>>(lf, rf, out);
}